// Round 5
// baseline (1247.050 us; speedup 1.0000x reference)
//
#include <hip/hip_runtime.h>

#define BB 16
#define CC 256
#define NN 4096
#define MM 1024
#define EPSV 1e-5f
#define SCALE (1.0f/16.0f)   // 1/sqrt(C)

// ---- workspace layout (float offsets). Total 23,499,776 floats = ~94 MB ----
#define OFF_MU    0            // 4096
#define OFF_SCORE 4096         // 65536
#define OFF_IDX   69632        // 32768 ints (idx_s then idx_g)
#define OFF_U     102400       // 65536
#define OFF_WVZ   167936       // 65536
#define OFF_WF12  233472       // 65536
#define OFF_BVZ   299008       // 256
#define OFF_BZ    299264       // 256
#define OFF_W16   299520       // 4 bf16 weight mats: Wf12,Wq,Wk,Wvz = 131072 floats
#define OFF_XG    430592       // Xg bf16 [16*1024][256] = 2097152 floats
#define OFF_K16   2527744      // K bf16 [B][M][C] = 2097152 floats
#define OFF_VT16  4624896      // Vt bf16 [B][C][M] = 2097152 floats
#define OFF_Z     6722048      // 16777216 floats
#define OFF_BN    23499264     // 512

typedef __attribute__((ext_vector_type(8))) short s16x8;
typedef __attribute__((ext_vector_type(4))) float f32x4;
typedef __attribute__((ext_vector_type(16))) float f32x16;

__device__ __forceinline__ unsigned short f2bf(float f) {
    unsigned int u = __float_as_uint(f);
    return (unsigned short)((u + 0x7FFFu + ((u >> 16) & 1u)) >> 16);
}
__device__ __forceinline__ float bf2f(unsigned short h) {
    return __uint_as_float(((unsigned int)h) << 16);
}

// async global->LDS, 16 B per lane; LDS dst = wave-uniform base + lane*16
typedef const __attribute__((address_space(1))) unsigned int* gas_t;
typedef __attribute__((address_space(3))) unsigned int* las_t;
__device__ __forceinline__ void gl2lds16(const void* g, void* l) {
    __builtin_amdgcn_global_load_lds((gas_t)g, (las_t)l, 16, 0, 0);
}

__global__ __launch_bounds__(256) void zero_bn_kernel(float* bn) {
    int t = threadIdx.x;
    bn[t] = 0.f; bn[t + CC] = 0.f;
}

// mu[b,c] = mean over n of x[b,c,n]
__global__ __launch_bounds__(256) void mean_kernel(const float* __restrict__ x, float* __restrict__ mu) {
    int c = blockIdx.x, b = blockIdx.y, t = threadIdx.x;
    const float* p = x + ((size_t)b * CC + c) * NN;
    float s = 0.f;
    for (int n = t; n < NN; n += 256) s += p[n];
    __shared__ float red[256];
    red[t] = s; __syncthreads();
    for (int w = 128; w > 0; w >>= 1) { if (t < w) red[t] += red[t + w]; __syncthreads(); }
    if (t == 0) mu[b * CC + c] = red[0] * (1.0f / NN);
}

// score[b,n] = sum_c (x[b,c,n]-mu[b,c])^2
__global__ __launch_bounds__(256) void score_kernel(const float* __restrict__ x, const float* __restrict__ mu,
                                                    float* __restrict__ score) {
    int b = blockIdx.y, t = threadIdx.x;
    int n = blockIdx.x * 256 + t;
    __shared__ float smu[CC];
    smu[t] = mu[b * CC + t];
    __syncthreads();
    float acc = 0.f;
    const float* p = x + (size_t)b * CC * NN + n;
    for (int c = 0; c < CC; ++c) { float d = p[(size_t)c * NN] - smu[c]; acc += d * d; }
    score[b * NN + n] = acc;
}

// bitonic sort 4096 (score,idx) descending per batch; head 1024 -> idx_s, tail 1024 -> idx_g
__global__ __launch_bounds__(1024) void topk_kernel(const float* __restrict__ score,
                                                    int* __restrict__ idx_s, int* __restrict__ idx_g) {
    int b = blockIdx.x, t = threadIdx.x;
    __shared__ float v[NN];
    __shared__ int   id[NN];
    for (int q = t; q < NN; q += 1024) { v[q] = score[b * NN + q]; id[q] = q; }
    __syncthreads();
    for (int k = 2; k <= NN; k <<= 1) {
        for (int j = k >> 1; j > 0; j >>= 1) {
            for (int q = t; q < NN; q += 1024) {
                int ixj = q ^ j;
                if (ixj > q) {
                    float va = v[q], vb = v[ixj];
                    int ia = id[q], ib = id[ixj];
                    bool before = (va > vb) || (va == vb && ia < ib);
                    bool descBlock = ((q & k) == 0);
                    bool doswap = descBlock ? (!before) : before;
                    if (doswap) { v[q] = vb; v[ixj] = va; id[q] = ib; id[ixj] = ia; }
                }
            }
            __syncthreads();
        }
    }
    if (t < MM) {
        idx_s[b * MM + t] = id[t];
        idx_g[b * MM + t] = id[NN - MM + t];
    }
}

// Cm[e,f] = sum_k A[e*lda+aoff+k] * Bm[k*CC+f]
__global__ __launch_bounds__(256) void smallmm_kernel(const float* __restrict__ A, int lda, int aoff,
                                                      const float* __restrict__ Bm, float* __restrict__ Cm) {
    int e = blockIdx.x, t = threadIdx.x;
    __shared__ float arow[CC];
    arow[t] = A[e * lda + aoff + t];
    __syncthreads();
    float acc = 0.f;
    for (int k = 0; k < CC; ++k) acc += arow[k] * Bm[k * CC + t];
    Cm[e * CC + t] = acc;
}

__global__ __launch_bounds__(256) void bvz_kernel(const float* __restrict__ U, const float* __restrict__ bv,
                                                  float* __restrict__ bvz) {
    int e = threadIdx.x;
    float acc = 0.f;
    for (int d = 0; d < CC; ++d) acc += U[e * CC + d] * bv[d];
    bvz[e] = acc;
}

__global__ __launch_bounds__(256) void bz_kernel(const float* __restrict__ Wf, const float* __restrict__ bf,
                                                 const float* __restrict__ bo_s, const float* __restrict__ bo_g,
                                                 float* __restrict__ bz) {
    int e = threadIdx.x;
    float acc = bf[e];
    for (int c = 0; c < CC; ++c)
        acc += Wf[e * 2 * CC + c] * bo_s[c] + Wf[e * 2 * CC + CC + c] * bo_g[c];
    bz[e] = acc;
}

__global__ __launch_bounds__(256) void wf12_kernel(const float* __restrict__ Wf, float* __restrict__ Wf12) {
    int e = blockIdx.x, c = threadIdx.x;
    Wf12[e * CC + c] = Wf[e * 2 * CC + c] + Wf[e * 2 * CC + CC + c];
}

// f32 -> bf16 (n multiple of 1024; 4 elems/thread)
__global__ __launch_bounds__(256) void conv_bf16_kernel(const float* __restrict__ src,
                                                        unsigned short* __restrict__ dst) {
    int i = blockIdx.x * 256 + threadIdx.x;
    float4 v = *(const float4*)(src + (size_t)i * 4);
    uint2 p;
    p.x = (unsigned int)f2bf(v.x) | ((unsigned int)f2bf(v.y) << 16);
    p.y = (unsigned int)f2bf(v.z) | ((unsigned int)f2bf(v.w) << 16);
    *(uint2*)&dst[(size_t)i * 4] = p;
}

// x [B][C][N] f32 -> xT16 [B][N][C] bf16
__global__ __launch_bounds__(256) void transpose_x_kernel(const float* __restrict__ x,
                                                          unsigned short* __restrict__ xT) {
    __shared__ float tile[32][33];
    int b = blockIdx.z, c0 = blockIdx.y * 32, n0 = blockIdx.x * 32, t = threadIdx.x;
    int nl = t & 31, cr = t >> 5;
#pragma unroll
    for (int q = 0; q < 4; ++q)
        tile[cr + q * 8][nl] = x[((size_t)b * CC + c0 + cr + q * 8) * NN + n0 + nl];
    __syncthreads();
    int nr = t >> 3, cq = t & 7;
    uint2 p;
    p.x = (unsigned int)f2bf(tile[cq * 4 + 0][nr]) | ((unsigned int)f2bf(tile[cq * 4 + 1][nr]) << 16);
    p.y = (unsigned int)f2bf(tile[cq * 4 + 2][nr]) | ((unsigned int)f2bf(tile[cq * 4 + 3][nr]) << 16);
    *(uint2*)&xT[((size_t)b * NN + n0 + nr) * CC + c0 + cq * 4] = p;
}

// Xg[row][c] = xT[b][idx[row]][c], row in [0, B*M)
__global__ __launch_bounds__(256) void gather_kernel(const unsigned short* __restrict__ xT,
                                                     const int* __restrict__ idx,
                                                     unsigned short* __restrict__ Xg) {
    int row = blockIdx.x * 4 + (threadIdx.x >> 6);
    int l = threadIdx.x & 63;
    int b = row >> 10, m = row & (MM - 1);
    int src = idx[b * MM + m];
    *(uint2*)&Xg[(size_t)row * CC + l * 4] =
        *(const uint2*)&xT[((size_t)b * NN + src) * CC + l * 4];
}

// ---- generic bf16 MFMA GEMM: out[i][j] = sum_k A[i][k]*Bw[j][k] (+bias), 128x128 tile ----
// OMODE 0: f32 out, bias[col]; 1: bf16 out, bias[col]; 2: bf16 out, bias[row]
template<int OMODE>
__global__ __launch_bounds__(256, 3) void gemm_bt(
    const unsigned short* __restrict__ A, size_t a_bs,
    const unsigned short* __restrict__ Bw, size_t b_bs,
    const float* __restrict__ bias,
    void* __restrict__ outp, size_t o_bs, int ldo)
{
    __shared__ __align__(16) unsigned short As[128 * 32];
    __shared__ __align__(16) unsigned short Bs[128 * 32];
    int z = blockIdx.z;
    const unsigned short* Ab = A + z * a_bs + (size_t)blockIdx.x * 128 * CC;
    const unsigned short* Bb = Bw + z * b_bs + (size_t)blockIdx.y * 128 * CC;
    int t = threadIdx.x, w = t >> 6, l = t & 63, g = l >> 4, c16 = l & 15;
    int wi = w >> 1, wj = w & 1;
    int srow = t >> 2, skq = (t & 3) * 8;

    f32x4 acc[4][4];
#pragma unroll
    for (int a = 0; a < 4; ++a)
#pragma unroll
        for (int bq = 0; bq < 4; ++bq) acc[a][bq] = (f32x4){0.f, 0.f, 0.f, 0.f};

    for (int ks = 0; ks < 8; ++ks) {
        int k0 = ks * 32;
        uint4 a0 = *(const uint4*)(Ab + (size_t)srow * CC + k0 + skq);
        uint4 a1 = *(const uint4*)(Ab + (size_t)(srow + 64) * CC + k0 + skq);
        uint4 b0 = *(const uint4*)(Bb + (size_t)srow * CC + k0 + skq);
        uint4 b1 = *(const uint4*)(Bb + (size_t)(srow + 64) * CC + k0 + skq);
        __syncthreads();
        *(uint4*)&As[srow * 32 + skq] = a0;
        *(uint4*)&As[(srow + 64) * 32 + skq] = a1;
        *(uint4*)&Bs[srow * 32 + skq] = b0;
        *(uint4*)&Bs[(srow + 64) * 32 + skq] = b1;
        __syncthreads();
        s16x8 af[4], bf4[4];
#pragma unroll
        for (int fi = 0; fi < 4; ++fi)
            af[fi] = *(const s16x8*)&As[(wi * 64 + fi * 16 + c16) * 32 + g * 8];
#pragma unroll
        for (int fj = 0; fj < 4; ++fj)
            bf4[fj] = *(const s16x8*)&Bs[(wj * 64 + fj * 16 + c16) * 32 + g * 8];
#pragma unroll
        for (int fi = 0; fi < 4; ++fi)
#pragma unroll
            for (int fj = 0; fj < 4; ++fj)
                acc[fi][fj] = __builtin_amdgcn_mfma_f32_16x16x32_bf16(af[fi], bf4[fj], acc[fi][fj], 0, 0, 0);
    }

    int i0 = blockIdx.x * 128 + wi * 64, j0 = blockIdx.y * 128 + wj * 64;
#pragma unroll
    for (int fi = 0; fi < 4; ++fi) {
#pragma unroll
        for (int fj = 0; fj < 4; ++fj) {
            int colg = j0 + fj * 16 + c16;
#pragma unroll
            for (int r = 0; r < 4; ++r) {
                int rowg = i0 + fi * 16 + g * 4 + r;
                float v = acc[fi][fj][r] + (OMODE == 2 ? bias[rowg] : bias[colg]);
                if (OMODE == 0)
                    ((float*)outp)[z * o_bs + (size_t)rowg * ldo + colg] = v;
                else
                    ((unsigned short*)outp)[z * o_bs + (size_t)rowg * ldo + colg] = f2bf(v);
            }
        }
    }
}

// ---- MFMA flash attention v4: 32x32x16 MFMA, async global_load_lds staging ----
// Block: 64 Q rows, 4 waves = (wq: q-half 32 rows) x (we: e-half 128 cols).
// M-step 32. LDS chunk-major (conflict-free b128 reads, lane-linear for async DMA).
// QK computed redundantly per e-half (MFMA has headroom; keeps waves independent).
__global__ __launch_bounds__(256) void attn_mfma4(
    const unsigned short* __restrict__ Qg,   // [B][N][C] bf16
    const unsigned short* __restrict__ Kg,   // [B][M][C] bf16
    const unsigned short* __restrict__ Vtg,  // [B][C][M] bf16
    float* __restrict__ Z)                   // [B][N][C] +=
{
    __shared__ __align__(16) unsigned short Ks[32 * 32 * 8];   // [chunk 32][row 32][8]  16 KB
    __shared__ __align__(16) unsigned short Vs[8 * 256 * 8];   // [chunk 8][e 256][8]    32 KB
    __shared__ __align__(16) unsigned short Ps[4 * 4 * 32 * 8];// per wave [chunk 4][row 32][8] 8 KB

    int b = blockIdx.y, n0 = blockIdx.x * 64, t = threadIdx.x;
    int w = t >> 6, l = t & 63, h = l >> 5, l31 = l & 31;
    int wq = w >> 1, we = w & 1;

    // Q frags (A-layout 32x32x16: row=lane&31, k=(lane>>5)*8+j), held whole kernel
    s16x8 qf[16];
    const unsigned short* qp = Qg + ((size_t)b * NN + n0 + wq * 32 + l31) * CC + h * 8;
#pragma unroll
    for (int kf = 0; kf < 16; ++kf) qf[kf] = *(const s16x8*)(qp + kf * 16);

    f32x16 O[4] = {};
    float rsum[16];
#pragma unroll
    for (int r = 0; r < 16; ++r) rsum[r] = 0.f;

    const unsigned short* Kb = Kg + (size_t)b * MM * CC;
    const unsigned short* Vb = Vtg + (size_t)b * CC * MM;

    for (int ms = 0; ms < 32; ++ms) {
        int m0 = ms * 32;
        __syncthreads();   // all waves done reading previous tile
        // stage K tile [32 m][256 c] chunk-major: region r = chunks {2r,2r+1}; lane: row=l31, chunk=2r+h
#pragma unroll
        for (int i = 0; i < 4; ++i) {
            int r = w * 4 + i;
            gl2lds16(Kb + ((size_t)(m0 + l31)) * CC + (2 * r + h) * 8, &Ks[r * 512]);
        }
        // stage V tile [256 e][32 m] chunk-major: region r: chunk=r>>2, e=(r&3)*64+l
#pragma unroll
        for (int i = 0; i < 8; ++i) {
            int r = w * 8 + i;
            gl2lds16(Vb + ((size_t)((r & 3) * 64 + l)) * MM + m0 + (r >> 2) * 8, &Vs[r * 512]);
        }
        __syncthreads();   // drains vmcnt: tile visible

        // S(32q x 32m) = Q K^T
        f32x16 S = {};
#pragma unroll
        for (int kf = 0; kf < 16; ++kf) {
            s16x8 kfr = *(const s16x8*)&Ks[(2 * kf + h) * 256 + l31 * 8];
            S = __builtin_amdgcn_mfma_f32_32x32x16_bf16(qf[kf], kfr, S, 0, 0, 0);
        }
        // exp (no max-sub: |s/16| small), bf16 round, Ps write (chunk-major), lane-local rsum
#pragma unroll
        for (int r = 0; r < 16; ++r) {
            float e = __expf(S[r] * SCALE);
            unsigned short hb = f2bf(e);
            int prow = (r & 3) + 8 * (r >> 2) + 4 * h;   // C/D row (m74/m101)
            Ps[w * 1024 + (l31 >> 3) * 256 + prow * 8 + (l31 & 7)] = hb;
            rsum[r] += bf2f(hb);
        }
        // O(32q x 128e) += P V   (Ps wave-private; compiler inserts lgkm waits)
#pragma unroll
        for (int kh = 0; kh < 2; ++kh) {
            s16x8 pf = *(const s16x8*)&Ps[w * 1024 + (2 * kh + h) * 256 + l31 * 8];
#pragma unroll
            for (int eg = 0; eg < 4; ++eg) {
                s16x8 vf = *(const s16x8*)&Vs[(2 * kh + h) * 2048 + (we * 128 + eg * 32 + l31) * 8];
                O[eg] = __builtin_amdgcn_mfma_f32_32x32x16_bf16(pf, vf, O[eg], 0, 0, 0);
            }
        }
    }

    // total row sums (rows owned per (r,h); lanes l31 hold col partials)
    float inv[16];
#pragma unroll
    for (int r = 0; r < 16; ++r) {
        float v = rsum[r];
        v += __shfl_xor(v, 1); v += __shfl_xor(v, 2); v += __shfl_xor(v, 4);
        v += __shfl_xor(v, 8); v += __shfl_xor(v, 16);
        inv[r] = 1.0f / v;
    }
    float* zb = Z + ((size_t)b * NN + n0 + wq * 32) * CC + we * 128 + l31;
#pragma unroll
    for (int eg = 0; eg < 4; ++eg)
#pragma unroll
        for (int r = 0; r < 16; ++r) {
            int prow = (r & 3) + 8 * (r >> 2) + 4 * h;
            zb[(size_t)prow * CC + eg * 32] += O[eg][r] * inv[r];
        }
}

// BN stats: per-channel sum and sumsq over B*N rows of Z [B*N][C]
__global__ __launch_bounds__(256) void bn_stats_kernel(const float* __restrict__ Z, float* __restrict__ bn) {
    int blk = blockIdx.x, e = threadIdx.x;
    const float* p = Z + (size_t)blk * 256 * CC + e;
    float s1 = 0.f, s2 = 0.f;
    for (int r = 0; r < 256; ++r) { float v = p[(size_t)r * CC]; s1 += v; s2 += v * v; }
    atomicAdd(&bn[e], s1);
    atomicAdd(&bn[CC + e], s2);
}

// normalize + relu + transpose [B][N][C] -> [B][C][N]
__global__ __launch_bounds__(256) void bn_apply_kernel(const float* __restrict__ Z, const float* __restrict__ bn,
                                                       const float* __restrict__ gamma, const float* __restrict__ beta,
                                                       float* __restrict__ out) {
    int b = blockIdx.z, e0 = blockIdx.y * 32, n0 = blockIdx.x * 32, t = threadIdx.x;
    __shared__ float tile[32][33];
    int c = t & 31, r0 = (t >> 5) * 4;
#pragma unroll
    for (int q = 0; q < 4; ++q)
        tile[r0 + q][c] = Z[((size_t)b * NN + n0 + r0 + q) * CC + e0 + c];
    __syncthreads();
    int n = t & 31, er0 = (t >> 5) * 4;
    const float invcnt = 1.0f / (BB * NN);
#pragma unroll
    for (int q = 0; q < 4; ++q) {
        int e = e0 + er0 + q;
        float mean = bn[e] * invcnt;
        float var = bn[CC + e] * invcnt - mean * mean;
        float rs = rsqrtf(var + EPSV);
        float v = (tile[n][er0 + q] - mean) * rs * gamma[e] + beta[e];
        out[((size_t)b * CC + e) * NN + n0 + n] = fmaxf(v, 0.f);
    }
}

extern "C" void kernel_launch(void* const* d_in, const int* in_sizes, int n_in,
                              void* d_out, int out_size, void* d_ws, size_t ws_size,
                              hipStream_t stream) {
    const float* x    = (const float*)d_in[0];
    const float* Wq_s = (const float*)d_in[2];  const float* bq_s = (const float*)d_in[3];
    const float* Wk_s = (const float*)d_in[4];  const float* bk_s = (const float*)d_in[5];
    const float* Wv_s = (const float*)d_in[6];  const float* bv_s = (const float*)d_in[7];
    const float* Wo_s = (const float*)d_in[8];  const float* bo_s = (const float*)d_in[9];
    const float* Wq_g = (const float*)d_in[10]; const float* bq_g = (const float*)d_in[11];
    const float* Wk_g = (const float*)d_in[12]; const float* bk_g = (const float*)d_in[13];
    const float* Wv_g = (const float*)d_in[14]; const float* bv_g = (const float*)d_in[15];
    const float* Wo_g = (const float*)d_in[16]; const float* bo_g = (const float*)d_in[17];
    const float* Wf   = (const float*)d_in[18]; const float* bf   = (const float*)d_in[19];
    const float* gamma = (const float*)d_in[20]; const float* beta = (const float*)d_in[21];

    float* ws    = (float*)d_ws;
    float* mu    = ws + OFF_MU;
    float* score = ws + OFF_SCORE;
    int*   idx_s = (int*)(ws + OFF_IDX);
    int*   idx_g = idx_s + BB * MM;
    float* U     = ws + OFF_U;
    float* Wvz   = ws + OFF_WVZ;
    float* Wf12  = ws + OFF_WF12;
    float* bvz   = ws + OFF_BVZ;
    float* bz    = ws + OFF_BZ;
    unsigned short* Wf12_16 = (unsigned short*)(ws + OFF_W16);
    unsigned short* Wq16    = Wf12_16 + 65536;
    unsigned short* Wk16    = Wq16 + 65536;
    unsigned short* Wvz16   = Wk16 + 65536;
    unsigned short* Xg16 = (unsigned short*)(ws + OFF_XG);
    unsigned short* K16  = (unsigned short*)(ws + OFF_K16);
    unsigned short* Vt16 = (unsigned short*)(ws + OFF_VT16);
    float* Z     = ws + OFF_Z;
    float* bn    = ws + OFF_BN;
    // d_out doubles as scratch: first half Q16 bf16, second half xT16 bf16 (both dead before bn_apply)
    unsigned short* Q16  = (unsigned short*)d_out;
    unsigned short* xT16 = Q16 + (size_t)BB * NN * CC;

    zero_bn_kernel<<<1, 256, 0, stream>>>(bn);
    transpose_x_kernel<<<dim3(NN / 32, CC / 32, BB), 256, 0, stream>>>(x, xT16);
    mean_kernel<<<dim3(CC, BB), 256, 0, stream>>>(x, mu);
    score_kernel<<<dim3(NN / 256, BB), 256, 0, stream>>>(x, mu, score);
    topk_kernel<<<BB, 1024, 0, stream>>>(score, idx_s, idx_g);
    wf12_kernel<<<CC, 256, 0, stream>>>(Wf, Wf12);
    bz_kernel<<<1, 256, 0, stream>>>(Wf, bf, bo_s, bo_g, bz);
    conv_bf16_kernel<<<64, 256, 0, stream>>>(Wf12, Wf12_16);
    // Z = xT @ Wf12^T + bz  (residual x through both conv halves)
    gemm_bt<0><<<dim3(512, 2, 1), 256, 0, stream>>>(xT16, 0, Wf12_16, 0, bz, Z, 0, CC);

    for (int br = 0; br < 2; ++br) {
        const float* Wo = br ? Wo_g : Wo_s;
        const float* Wv = br ? Wv_g : Wv_s;  const float* bv = br ? bv_g : bv_s;
        const float* Wk = br ? Wk_g : Wk_s;  const float* bk = br ? bk_g : bk_s;
        const float* Wq = br ? Wq_g : Wq_s;  const float* bq = br ? bq_g : bq_s;
        int* idx = br ? idx_g : idx_s;
        int aoff = br ? CC : 0;
        // U = Wf_half @ Wo ; Wvz = U @ Wv ; bvz = U @ bv
        smallmm_kernel<<<CC, 256, 0, stream>>>(Wf, 2 * CC, aoff, Wo, U);
        smallmm_kernel<<<CC, 256, 0, stream>>>(U, CC, 0, Wv, Wvz);
        bvz_kernel<<<1, 256, 0, stream>>>(U, bv, bvz);
        conv_bf16_kernel<<<64, 256, 0, stream>>>(Wq, Wq16);
        conv_bf16_kernel<<<64, 256, 0, stream>>>(Wk, Wk16);
        conv_bf16_kernel<<<64, 256, 0, stream>>>(Wvz, Wvz16);
        // gather context rows once, then all projections are plain A*B^T GEMMs
        gather_kernel<<<BB * MM / 4, 256, 0, stream>>>(xT16, idx, Xg16);
        gemm_bt<1><<<dim3(BB * MM / 128, 2, 1), 256, 0, stream>>>(Xg16, 0, Wk16, 0, bk, K16, 0, CC);
        gemm_bt<2><<<dim3(2, 8, BB), 256, 0, stream>>>(Wvz16, 0, Xg16, (size_t)MM * CC, bvz,
                                                       Vt16, (size_t)CC * MM, MM);
        gemm_bt<1><<<dim3(512, 2, 1), 256, 0, stream>>>(xT16, 0, Wq16, 0, bq, Q16, 0, CC);
        // Z += softmax(QK^T/16) @ Vz
        attn_mfma4<<<dim3(NN / 64, BB), 256, 0, stream>>>(Q16, K16, Vt16, Z);
    }

    bn_stats_kernel<<<BB * NN / 256, 256, 0, stream>>>(Z, bn);
    bn_apply_kernel<<<dim3(NN / 32, CC / 32, BB), 256, 0, stream>>>(Z, bn, gamma, beta, (float*)d_out);
}

// Round 6
// 808.058 us; speedup vs baseline: 1.5433x; 1.5433x over previous
//
#include <hip/hip_runtime.h>

#define BB 16
#define CC 256
#define NN 4096
#define MM 1024
#define EPSV 1e-5f
#define SCALE (1.0f/16.0f)   // 1/sqrt(C)

// ---- workspace layout (float offsets). Fixed part 23,499,776 floats = ~94 MB ----
#define OFF_MU    0            // 4096
#define OFF_SCORE 4096         // 65536   (dead after topk -> reused as rsum when G==1)
#define OFF_IDX   69632        // 32768 ints (idx_s then idx_g)
#define OFF_U     102400       // 65536
#define OFF_WVZ   167936       // 65536
#define OFF_WF12  233472       // 65536
#define OFF_BVZ   299008       // 256
#define OFF_BZ    299264       // 256
#define OFF_W16   299520       // 4 bf16 weight mats = 131072 floats
#define OFF_XG    430592       // Xg bf16 [16*1024][256] = 2097152 floats (dead during attention)
#define OFF_K16   2527744      // K bf16 [B][M][C] = 2097152 floats
#define OFF_VT16  4624896      // Vt bf16 [B][C][M] = 2097152 floats
#define OFF_Z     6722048      // 16777216 floats
#define OFF_BN    23499264     // 512
#define FIXED_F   23499776     // end of fixed region (floats)

typedef __attribute__((ext_vector_type(8))) short s16x8;
typedef __attribute__((ext_vector_type(4))) float f32x4;

__device__ __forceinline__ unsigned short f2bf(float f) {
    unsigned int u = __float_as_uint(f);
    return (unsigned short)((u + 0x7FFFu + ((u >> 16) & 1u)) >> 16);
}
__device__ __forceinline__ float bf2f(unsigned short h) {
    return __uint_as_float(((unsigned int)h) << 16);
}

__global__ __launch_bounds__(256) void zero_bn_kernel(float* bn) {
    int t = threadIdx.x;
    bn[t] = 0.f; bn[t + CC] = 0.f;
}

__global__ __launch_bounds__(256) void zero_rsum_kernel(float* r) {
    r[blockIdx.x * 256 + threadIdx.x] = 0.f;
}

// mu[b,c] = mean over n of x[b,c,n]
__global__ __launch_bounds__(256) void mean_kernel(const float* __restrict__ x, float* __restrict__ mu) {
    int c = blockIdx.x, b = blockIdx.y, t = threadIdx.x;
    const float* p = x + ((size_t)b * CC + c) * NN;
    float s = 0.f;
    for (int n = t; n < NN; n += 256) s += p[n];
    __shared__ float red[256];
    red[t] = s; __syncthreads();
    for (int w = 128; w > 0; w >>= 1) { if (t < w) red[t] += red[t + w]; __syncthreads(); }
    if (t == 0) mu[b * CC + c] = red[0] * (1.0f / NN);
}

// score[b,n] = sum_c (x[b,c,n]-mu[b,c])^2
__global__ __launch_bounds__(256) void score_kernel(const float* __restrict__ x, const float* __restrict__ mu,
                                                    float* __restrict__ score) {
    int b = blockIdx.y, t = threadIdx.x;
    int n = blockIdx.x * 256 + t;
    __shared__ float smu[CC];
    smu[t] = mu[b * CC + t];
    __syncthreads();
    float acc = 0.f;
    const float* p = x + (size_t)b * CC * NN + n;
    for (int c = 0; c < CC; ++c) { float d = p[(size_t)c * NN] - smu[c]; acc += d * d; }
    score[b * NN + n] = acc;
}

// bitonic sort 4096 (score,idx) descending per batch; head 1024 -> idx_s, tail 1024 -> idx_g
__global__ __launch_bounds__(1024) void topk_kernel(const float* __restrict__ score,
                                                    int* __restrict__ idx_s, int* __restrict__ idx_g) {
    int b = blockIdx.x, t = threadIdx.x;
    __shared__ float v[NN];
    __shared__ int   id[NN];
    for (int q = t; q < NN; q += 1024) { v[q] = score[b * NN + q]; id[q] = q; }
    __syncthreads();
    for (int k = 2; k <= NN; k <<= 1) {
        for (int j = k >> 1; j > 0; j >>= 1) {
            for (int q = t; q < NN; q += 1024) {
                int ixj = q ^ j;
                if (ixj > q) {
                    float va = v[q], vb = v[ixj];
                    int ia = id[q], ib = id[ixj];
                    bool before = (va > vb) || (va == vb && ia < ib);
                    bool descBlock = ((q & k) == 0);
                    bool doswap = descBlock ? (!before) : before;
                    if (doswap) { v[q] = vb; v[ixj] = va; id[q] = ib; id[ixj] = ia; }
                }
            }
            __syncthreads();
        }
    }
    if (t < MM) {
        idx_s[b * MM + t] = id[t];
        idx_g[b * MM + t] = id[NN - MM + t];
    }
}

// Cm[e,f] = sum_k A[e*lda+aoff+k] * Bm[k*CC+f]
__global__ __launch_bounds__(256) void smallmm_kernel(const float* __restrict__ A, int lda, int aoff,
                                                      const float* __restrict__ Bm, float* __restrict__ Cm) {
    int e = blockIdx.x, t = threadIdx.x;
    __shared__ float arow[CC];
    arow[t] = A[e * lda + aoff + t];
    __syncthreads();
    float acc = 0.f;
    for (int k = 0; k < CC; ++k) acc += arow[k] * Bm[k * CC + t];
    Cm[e * CC + t] = acc;
}

__global__ __launch_bounds__(256) void bvz_kernel(const float* __restrict__ U, const float* __restrict__ bv,
                                                  float* __restrict__ bvz) {
    int e = threadIdx.x;
    float acc = 0.f;
    for (int d = 0; d < CC; ++d) acc += U[e * CC + d] * bv[d];
    bvz[e] = acc;
}

__global__ __launch_bounds__(256) void bz_kernel(const float* __restrict__ Wf, const float* __restrict__ bf,
                                                 const float* __restrict__ bo_s, const float* __restrict__ bo_g,
                                                 float* __restrict__ bz) {
    int e = threadIdx.x;
    float acc = bf[e];
    for (int c = 0; c < CC; ++c)
        acc += Wf[e * 2 * CC + c] * bo_s[c] + Wf[e * 2 * CC + CC + c] * bo_g[c];
    bz[e] = acc;
}

__global__ __launch_bounds__(256) void wf12_kernel(const float* __restrict__ Wf, float* __restrict__ Wf12) {
    int e = blockIdx.x, c = threadIdx.x;
    Wf12[e * CC + c] = Wf[e * 2 * CC + c] + Wf[e * 2 * CC + CC + c];
}

// f32 -> bf16 (n multiple of 1024; 4 elems/thread)
__global__ __launch_bounds__(256) void conv_bf16_kernel(const float* __restrict__ src,
                                                        unsigned short* __restrict__ dst) {
    int i = blockIdx.x * 256 + threadIdx.x;
    float4 v = *(const float4*)(src + (size_t)i * 4);
    uint2 p;
    p.x = (unsigned int)f2bf(v.x) | ((unsigned int)f2bf(v.y) << 16);
    p.y = (unsigned int)f2bf(v.z) | ((unsigned int)f2bf(v.w) << 16);
    *(uint2*)&dst[(size_t)i * 4] = p;
}

// x [B][C][N] f32 -> xT16 [B][N][C] bf16
__global__ __launch_bounds__(256) void transpose_x_kernel(const float* __restrict__ x,
                                                          unsigned short* __restrict__ xT) {
    __shared__ float tile[32][33];
    int b = blockIdx.z, c0 = blockIdx.y * 32, n0 = blockIdx.x * 32, t = threadIdx.x;
    int nl = t & 31, cr = t >> 5;
#pragma unroll
    for (int q = 0; q < 4; ++q)
        tile[cr + q * 8][nl] = x[((size_t)b * CC + c0 + cr + q * 8) * NN + n0 + nl];
    __syncthreads();
    int nr = t >> 3, cq = t & 7;
    uint2 p;
    p.x = (unsigned int)f2bf(tile[cq * 4 + 0][nr]) | ((unsigned int)f2bf(tile[cq * 4 + 1][nr]) << 16);
    p.y = (unsigned int)f2bf(tile[cq * 4 + 2][nr]) | ((unsigned int)f2bf(tile[cq * 4 + 3][nr]) << 16);
    *(uint2*)&xT[((size_t)b * NN + n0 + nr) * CC + c0 + cq * 4] = p;
}

// Xg[row][c] = xT[b][idx[row]][c], row in [0, B*M)
__global__ __launch_bounds__(256) void gather_kernel(const unsigned short* __restrict__ xT,
                                                     const int* __restrict__ idx,
                                                     unsigned short* __restrict__ Xg) {
    int row = blockIdx.x * 4 + (threadIdx.x >> 6);
    int l = threadIdx.x & 63;
    int b = row >> 10, m = row & (MM - 1);
    int src = idx[b * MM + m];
    *(uint2*)&Xg[(size_t)row * CC + l * 4] =
        *(const uint2*)&xT[((size_t)b * NN + src) * CC + l * 4];
}

// ---- generic bf16 MFMA GEMM: out[i][j] = sum_k A[i][k]*Bw[j][k] (+bias), 128x128 tile ----
// OMODE 0: f32 out, bias[col]; 1: bf16 out, bias[col]; 2: bf16 out, bias[row]
template<int OMODE>
__global__ __launch_bounds__(256, 3) void gemm_bt(
    const unsigned short* __restrict__ A, size_t a_bs,
    const unsigned short* __restrict__ Bw, size_t b_bs,
    const float* __restrict__ bias,
    void* __restrict__ outp, size_t o_bs, int ldo)
{
    __shared__ __align__(16) unsigned short As[128 * 32];
    __shared__ __align__(16) unsigned short Bs[128 * 32];
    int z = blockIdx.z;
    const unsigned short* Ab = A + z * a_bs + (size_t)blockIdx.x * 128 * CC;
    const unsigned short* Bb = Bw + z * b_bs + (size_t)blockIdx.y * 128 * CC;
    int t = threadIdx.x, w = t >> 6, l = t & 63, g = l >> 4, c16 = l & 15;
    int wi = w >> 1, wj = w & 1;
    int srow = t >> 2, skq = (t & 3) * 8;

    f32x4 acc[4][4];
#pragma unroll
    for (int a = 0; a < 4; ++a)
#pragma unroll
        for (int bq = 0; bq < 4; ++bq) acc[a][bq] = (f32x4){0.f, 0.f, 0.f, 0.f};

    for (int ks = 0; ks < 8; ++ks) {
        int k0 = ks * 32;
        uint4 a0 = *(const uint4*)(Ab + (size_t)srow * CC + k0 + skq);
        uint4 a1 = *(const uint4*)(Ab + (size_t)(srow + 64) * CC + k0 + skq);
        uint4 b0 = *(const uint4*)(Bb + (size_t)srow * CC + k0 + skq);
        uint4 b1 = *(const uint4*)(Bb + (size_t)(srow + 64) * CC + k0 + skq);
        __syncthreads();
        *(uint4*)&As[srow * 32 + skq] = a0;
        *(uint4*)&As[(srow + 64) * 32 + skq] = a1;
        *(uint4*)&Bs[srow * 32 + skq] = b0;
        *(uint4*)&Bs[(srow + 64) * 32 + skq] = b1;
        __syncthreads();
        s16x8 af[4], bf4[4];
#pragma unroll
        for (int fi = 0; fi < 4; ++fi)
            af[fi] = *(const s16x8*)&As[(wi * 64 + fi * 16 + c16) * 32 + g * 8];
#pragma unroll
        for (int fj = 0; fj < 4; ++fj)
            bf4[fj] = *(const s16x8*)&Bs[(wj * 64 + fj * 16 + c16) * 32 + g * 8];
#pragma unroll
        for (int fi = 0; fi < 4; ++fi)
#pragma unroll
            for (int fj = 0; fj < 4; ++fj)
                acc[fi][fj] = __builtin_amdgcn_mfma_f32_16x16x32_bf16(af[fi], bf4[fj], acc[fi][fj], 0, 0, 0);
    }

    int i0 = blockIdx.x * 128 + wi * 64, j0 = blockIdx.y * 128 + wj * 64;
#pragma unroll
    for (int fi = 0; fi < 4; ++fi) {
#pragma unroll
        for (int fj = 0; fj < 4; ++fj) {
            int colg = j0 + fj * 16 + c16;
#pragma unroll
            for (int r = 0; r < 4; ++r) {
                int rowg = i0 + fi * 16 + g * 4 + r;
                float v = acc[fi][fj][r] + (OMODE == 2 ? bias[rowg] : bias[colg]);
                if (OMODE == 0)
                    ((float*)outp)[z * o_bs + (size_t)rowg * ldo + colg] = v;
                else
                    ((unsigned short*)outp)[z * o_bs + (size_t)rowg * ldo + colg] = f2bf(v);
            }
        }
    }
}

// ---- attention GEMM 1: P[z][n][m] = bf16(exp(Q·K^T/16)), rsum[z][n] += row sums ----
__global__ __launch_bounds__(256, 3) void attn_gemm1(
    const unsigned short* __restrict__ Q,   // [G][N][C]
    const unsigned short* __restrict__ K,   // [G][M][C]
    unsigned short* __restrict__ P,         // [G][N][M]
    float* __restrict__ rsum)               // [G][N] (pre-zeroed)
{
    __shared__ __align__(16) unsigned short As[128 * 32];
    __shared__ __align__(16) unsigned short Bs[128 * 32];
    int z = blockIdx.z;
    const unsigned short* Ab = Q + (size_t)z * NN * CC + (size_t)blockIdx.x * 128 * CC;
    const unsigned short* Bb = K + (size_t)z * MM * CC + (size_t)blockIdx.y * 128 * CC;
    int t = threadIdx.x, w = t >> 6, l = t & 63, g = l >> 4, c16 = l & 15;
    int wi = w >> 1, wj = w & 1;
    int srow = t >> 2, skq = (t & 3) * 8;

    f32x4 acc[4][4];
#pragma unroll
    for (int a = 0; a < 4; ++a)
#pragma unroll
        for (int bq = 0; bq < 4; ++bq) acc[a][bq] = (f32x4){0.f, 0.f, 0.f, 0.f};

    for (int ks = 0; ks < 8; ++ks) {
        int k0 = ks * 32;
        uint4 a0 = *(const uint4*)(Ab + (size_t)srow * CC + k0 + skq);
        uint4 a1 = *(const uint4*)(Ab + (size_t)(srow + 64) * CC + k0 + skq);
        uint4 b0 = *(const uint4*)(Bb + (size_t)srow * CC + k0 + skq);
        uint4 b1 = *(const uint4*)(Bb + (size_t)(srow + 64) * CC + k0 + skq);
        __syncthreads();
        *(uint4*)&As[srow * 32 + skq] = a0;
        *(uint4*)&As[(srow + 64) * 32 + skq] = a1;
        *(uint4*)&Bs[srow * 32 + skq] = b0;
        *(uint4*)&Bs[(srow + 64) * 32 + skq] = b1;
        __syncthreads();
        s16x8 af[4], bf4[4];
#pragma unroll
        for (int fi = 0; fi < 4; ++fi)
            af[fi] = *(const s16x8*)&As[(wi * 64 + fi * 16 + c16) * 32 + g * 8];
#pragma unroll
        for (int fj = 0; fj < 4; ++fj)
            bf4[fj] = *(const s16x8*)&Bs[(wj * 64 + fj * 16 + c16) * 32 + g * 8];
#pragma unroll
        for (int fi = 0; fi < 4; ++fi)
#pragma unroll
            for (int fj = 0; fj < 4; ++fj)
                acc[fi][fj] = __builtin_amdgcn_mfma_f32_16x16x32_bf16(af[fi], bf4[fj], acc[fi][fj], 0, 0, 0);
    }

    int i0 = blockIdx.x * 128 + wi * 64, j0 = blockIdx.y * 128 + wj * 64;
    unsigned short* Pb = P + (size_t)z * NN * MM;
    float rs[4][4];
#pragma unroll
    for (int fi = 0; fi < 4; ++fi)
#pragma unroll
        for (int r = 0; r < 4; ++r) rs[fi][r] = 0.f;
#pragma unroll
    for (int fi = 0; fi < 4; ++fi)
#pragma unroll
        for (int fj = 0; fj < 4; ++fj)
#pragma unroll
            for (int r = 0; r < 4; ++r) {
                float e = __expf(acc[fi][fj][r] * SCALE);   // no max-sub: |s/16| small
                unsigned short h = f2bf(e);
                Pb[(size_t)(i0 + fi * 16 + g * 4 + r) * MM + j0 + fj * 16 + c16] = h;
                rs[fi][r] += bf2f(h);                       // sum bf16-rounded P (consistency)
            }
#pragma unroll
    for (int fi = 0; fi < 4; ++fi)
#pragma unroll
        for (int r = 0; r < 4; ++r) {
            float v = rs[fi][r];
            v += __shfl_xor(v, 1); v += __shfl_xor(v, 2);
            v += __shfl_xor(v, 4); v += __shfl_xor(v, 8);
            if (c16 == 0)
                atomicAdd(&rsum[(size_t)z * NN + i0 + fi * 16 + g * 4 + r], v);
        }
}

// ---- attention GEMM 2: Z[z][n][e] += (P·Vt^T) / rsum[n]; optional split-K ----
template<int SPLIT>
__global__ __launch_bounds__(256, 3) void attn_gemm2(
    const unsigned short* __restrict__ P,    // [G][N][M]
    const unsigned short* __restrict__ Vt,   // [G][C][M]
    const float* __restrict__ rsum,          // [G][N]
    float* __restrict__ Z)                   // [G][N][C] +=
{
    __shared__ __align__(16) unsigned short As[128 * 32];
    __shared__ __align__(16) unsigned short Bs[128 * 32];
    int zb = blockIdx.z / SPLIT, sp = blockIdx.z % SPLIT;
    int koff = sp * (MM / SPLIT);
    const unsigned short* Ab = P + (size_t)zb * NN * MM + (size_t)blockIdx.x * 128 * MM + koff;
    const unsigned short* Bb = Vt + (size_t)zb * CC * MM + (size_t)blockIdx.y * 128 * MM + koff;
    int t = threadIdx.x, w = t >> 6, l = t & 63, g = l >> 4, c16 = l & 15;
    int wi = w >> 1, wj = w & 1;
    int srow = t >> 2, skq = (t & 3) * 8;

    f32x4 acc[4][4];
#pragma unroll
    for (int a = 0; a < 4; ++a)
#pragma unroll
        for (int bq = 0; bq < 4; ++bq) acc[a][bq] = (f32x4){0.f, 0.f, 0.f, 0.f};

    for (int ks = 0; ks < 32 / SPLIT; ++ks) {
        int k0 = ks * 32;
        uint4 a0 = *(const uint4*)(Ab + (size_t)srow * MM + k0 + skq);
        uint4 a1 = *(const uint4*)(Ab + (size_t)(srow + 64) * MM + k0 + skq);
        uint4 b0 = *(const uint4*)(Bb + (size_t)srow * MM + k0 + skq);
        uint4 b1 = *(const uint4*)(Bb + (size_t)(srow + 64) * MM + k0 + skq);
        __syncthreads();
        *(uint4*)&As[srow * 32 + skq] = a0;
        *(uint4*)&As[(srow + 64) * 32 + skq] = a1;
        *(uint4*)&Bs[srow * 32 + skq] = b0;
        *(uint4*)&Bs[(srow + 64) * 32 + skq] = b1;
        __syncthreads();
        s16x8 af[4], bf4[4];
#pragma unroll
        for (int fi = 0; fi < 4; ++fi)
            af[fi] = *(const s16x8*)&As[(wi * 64 + fi * 16 + c16) * 32 + g * 8];
#pragma unroll
        for (int fj = 0; fj < 4; ++fj)
            bf4[fj] = *(const s16x8*)&Bs[(wj * 64 + fj * 16 + c16) * 32 + g * 8];
#pragma unroll
        for (int fi = 0; fi < 4; ++fi)
#pragma unroll
            for (int fj = 0; fj < 4; ++fj)
                acc[fi][fj] = __builtin_amdgcn_mfma_f32_16x16x32_bf16(af[fi], bf4[fj], acc[fi][fj], 0, 0, 0);
    }

    int i0 = blockIdx.x * 128 + wi * 64, j0 = blockIdx.y * 128 + wj * 64;
    float* Zb = Z + (size_t)zb * NN * CC;
#pragma unroll
    for (int fi = 0; fi < 4; ++fi)
#pragma unroll
        for (int r = 0; r < 4; ++r) {
            int rowg = i0 + fi * 16 + g * 4 + r;
            float inv = 1.0f / rsum[(size_t)zb * NN + rowg];
#pragma unroll
            for (int fj = 0; fj < 4; ++fj) {
                int colg = j0 + fj * 16 + c16;
                float v = acc[fi][fj][r] * inv;
                if (SPLIT > 1)
                    atomicAdd(&Zb[(size_t)rowg * CC + colg], v);
                else
                    Zb[(size_t)rowg * CC + colg] += v;
            }
        }
}

// BN stats: per-channel sum and sumsq over B*N rows of Z [B*N][C]
__global__ __launch_bounds__(256) void bn_stats_kernel(const float* __restrict__ Z, float* __restrict__ bn) {
    int blk = blockIdx.x, e = threadIdx.x;
    const float* p = Z + (size_t)blk * 256 * CC + e;
    float s1 = 0.f, s2 = 0.f;
    for (int r = 0; r < 256; ++r) { float v = p[(size_t)r * CC]; s1 += v; s2 += v * v; }
    atomicAdd(&bn[e], s1);
    atomicAdd(&bn[CC + e], s2);
}

// normalize + relu + transpose [B][N][C] -> [B][C][N]
__global__ __launch_bounds__(256) void bn_apply_kernel(const float* __restrict__ Z, const float* __restrict__ bn,
                                                       const float* __restrict__ gamma, const float* __restrict__ beta,
                                                       float* __restrict__ out) {
    int b = blockIdx.z, e0 = blockIdx.y * 32, n0 = blockIdx.x * 32, t = threadIdx.x;
    __shared__ float tile[32][33];
    int c = t & 31, r0 = (t >> 5) * 4;
#pragma unroll
    for (int q = 0; q < 4; ++q)
        tile[r0 + q][c] = Z[((size_t)b * NN + n0 + r0 + q) * CC + e0 + c];
    __syncthreads();
    int n = t & 31, er0 = (t >> 5) * 4;
    const float invcnt = 1.0f / (BB * NN);
#pragma unroll
    for (int q = 0; q < 4; ++q) {
        int e = e0 + er0 + q;
        float mean = bn[e] * invcnt;
        float var = bn[CC + e] * invcnt - mean * mean;
        float rs = rsqrtf(var + EPSV);
        float v = (tile[n][er0 + q] - mean) * rs * gamma[e] + beta[e];
        out[((size_t)b * CC + e) * NN + n0 + n] = fmaxf(v, 0.f);
    }
}

extern "C" void kernel_launch(void* const* d_in, const int* in_sizes, int n_in,
                              void* d_out, int out_size, void* d_ws, size_t ws_size,
                              hipStream_t stream) {
    const float* x    = (const float*)d_in[0];
    const float* Wq_s = (const float*)d_in[2];  const float* bq_s = (const float*)d_in[3];
    const float* Wk_s = (const float*)d_in[4];  const float* bk_s = (const float*)d_in[5];
    const float* Wv_s = (const float*)d_in[6];  const float* bv_s = (const float*)d_in[7];
    const float* Wo_s = (const float*)d_in[8];  const float* bo_s = (const float*)d_in[9];
    const float* Wq_g = (const float*)d_in[10]; const float* bq_g = (const float*)d_in[11];
    const float* Wk_g = (const float*)d_in[12]; const float* bk_g = (const float*)d_in[13];
    const float* Wv_g = (const float*)d_in[14]; const float* bv_g = (const float*)d_in[15];
    const float* Wo_g = (const float*)d_in[16]; const float* bo_g = (const float*)d_in[17];
    const float* Wf   = (const float*)d_in[18]; const float* bf   = (const float*)d_in[19];
    const float* gamma = (const float*)d_in[20]; const float* beta = (const float*)d_in[21];

    float* ws    = (float*)d_ws;
    float* mu    = ws + OFF_MU;
    float* score = ws + OFF_SCORE;
    int*   idx_s = (int*)(ws + OFF_IDX);
    int*   idx_g = idx_s + BB * MM;
    float* U     = ws + OFF_U;
    float* Wvz   = ws + OFF_WVZ;
    float* Wf12  = ws + OFF_WF12;
    float* bvz   = ws + OFF_BVZ;
    float* bz    = ws + OFF_BZ;
    unsigned short* Wf12_16 = (unsigned short*)(ws + OFF_W16);
    unsigned short* Wq16    = Wf12_16 + 65536;
    unsigned short* Wk16    = Wq16 + 65536;
    unsigned short* Wvz16   = Wk16 + 65536;
    unsigned short* Xg16 = (unsigned short*)(ws + OFF_XG);
    unsigned short* K16  = (unsigned short*)(ws + OFF_K16);
    unsigned short* Vt16 = (unsigned short*)(ws + OFF_VT16);
    float* Z     = ws + OFF_Z;
    float* bn    = ws + OFF_BN;
    // d_out doubles as scratch: first half Q16, second half xT16 (both dead before bn_apply)
    unsigned short* Q16  = (unsigned short*)d_out;
    unsigned short* xT16 = Q16 + (size_t)BB * NN * CC;

    // ---- batch-group size for materialized P, chosen from ws_size ----
    const size_t PGRP = (size_t)NN * MM / 2;   // floats per batch of P (bf16)
    size_t availF = ws_size / 4 > (size_t)FIXED_F ? ws_size / 4 - FIXED_F : 0;
    int G = 1;
    if (availF >= 8 * PGRP + 8 * NN) G = 8;
    else if (availF >= 4 * PGRP + 4 * NN) G = 4;
    else if (availF >= 2 * PGRP + 2 * NN) G = 2;
    unsigned short* Pbuf;
    float* rsumBuf;
    if (G > 1) {
        Pbuf = (unsigned short*)(ws + FIXED_F);
        rsumBuf = ws + FIXED_F + (size_t)G * PGRP;
    } else {
        Pbuf = Xg16;        // Xg dead during attention; regenerated next branch
        rsumBuf = score;    // score dead after topk
    }

    zero_bn_kernel<<<1, 256, 0, stream>>>(bn);
    transpose_x_kernel<<<dim3(NN / 32, CC / 32, BB), 256, 0, stream>>>(x, xT16);
    mean_kernel<<<dim3(CC, BB), 256, 0, stream>>>(x, mu);
    score_kernel<<<dim3(NN / 256, BB), 256, 0, stream>>>(x, mu, score);
    topk_kernel<<<BB, 1024, 0, stream>>>(score, idx_s, idx_g);
    wf12_kernel<<<CC, 256, 0, stream>>>(Wf, Wf12);
    bz_kernel<<<1, 256, 0, stream>>>(Wf, bf, bo_s, bo_g, bz);
    conv_bf16_kernel<<<64, 256, 0, stream>>>(Wf12, Wf12_16);
    // Z = xT @ Wf12^T + bz  (residual x through both conv halves)
    gemm_bt<0><<<dim3(512, 2, 1), 256, 0, stream>>>(xT16, 0, Wf12_16, 0, bz, Z, 0, CC);

    for (int br = 0; br < 2; ++br) {
        const float* Wo = br ? Wo_g : Wo_s;
        const float* Wv = br ? Wv_g : Wv_s;  const float* bv = br ? bv_g : bv_s;
        const float* Wk = br ? Wk_g : Wk_s;  const float* bk = br ? bk_g : bk_s;
        const float* Wq = br ? Wq_g : Wq_s;  const float* bq = br ? bq_g : bq_s;
        int* idx = br ? idx_g : idx_s;
        int aoff = br ? CC : 0;
        // U = Wf_half @ Wo ; Wvz = U @ Wv ; bvz = U @ bv
        smallmm_kernel<<<CC, 256, 0, stream>>>(Wf, 2 * CC, aoff, Wo, U);
        smallmm_kernel<<<CC, 256, 0, stream>>>(U, CC, 0, Wv, Wvz);
        bvz_kernel<<<1, 256, 0, stream>>>(U, bv, bvz);
        conv_bf16_kernel<<<64, 256, 0, stream>>>(Wq, Wq16);
        conv_bf16_kernel<<<64, 256, 0, stream>>>(Wk, Wk16);
        conv_bf16_kernel<<<64, 256, 0, stream>>>(Wvz, Wvz16);
        // gather context rows once, then all projections are plain A*B^T GEMMs
        gather_kernel<<<BB * MM / 4, 256, 0, stream>>>(xT16, idx, Xg16);
        gemm_bt<1><<<dim3(BB * MM / 128, 2, 1), 256, 0, stream>>>(Xg16, 0, Wk16, 0, bk, K16, 0, CC);
        gemm_bt<2><<<dim3(2, 8, BB), 256, 0, stream>>>(Wvz16, 0, Xg16, (size_t)MM * CC, bvz,
                                                       Vt16, (size_t)CC * MM, MM);
        gemm_bt<1><<<dim3(512, 2, 1), 256, 0, stream>>>(xT16, 0, Wq16, 0, bq, Q16, 0, CC);

        // attention as two GEMMs over batch groups of G
        for (int gb = 0; gb < BB; gb += G) {
            zero_rsum_kernel<<<G * (NN / 256), 256, 0, stream>>>(rsumBuf);
            attn_gemm1<<<dim3(NN / 128, MM / 128, G), 256, 0, stream>>>(
                Q16 + (size_t)gb * NN * CC, K16 + (size_t)gb * MM * CC, Pbuf, rsumBuf);
            if (G >= 8)
                attn_gemm2<1><<<dim3(NN / 128, CC / 128, G), 256, 0, stream>>>(
                    Pbuf, Vt16 + (size_t)gb * CC * MM, rsumBuf, Z + (size_t)gb * NN * CC);
            else if (G >= 2)
                attn_gemm2<2><<<dim3(NN / 128, CC / 128, G * 2), 256, 0, stream>>>(
                    Pbuf, Vt16 + (size_t)gb * CC * MM, rsumBuf, Z + (size_t)gb * NN * CC);
            else
                attn_gemm2<4><<<dim3(NN / 128, CC / 128, 4), 256, 0, stream>>>(
                    Pbuf, Vt16 + (size_t)gb * CC * MM, rsumBuf, Z + (size_t)gb * NN * CC);
        }
    }

    bn_stats_kernel<<<BB * NN / 256, 256, 0, stream>>>(Z, bn);
    bn_apply_kernel<<<dim3(NN / 32, CC / 32, BB), 256, 0, stream>>>(Z, bn, gamma, beta, (float*)d_out);
}